// Round 1
// baseline (2455.480 us; speedup 1.0000x reference)
//
#include <hip/hip_runtime.h>
#include <hip/hip_bf16.h>
#include <math.h>

#define BB 2
#define NN 768
#define DD 512
#define HH 16
#define DHH 32
#define PDD 128
#define ROWS (BB*NN)          // 1536

// workspace offsets (floats)
#define WC_OFF   0L           // 2048: pnw[e]*bias_w[e,h]
#define C12_OFF  2048L        // 16 c1 + 16 c2
#define X_OFF    4096L
#define QKV_OFF  (X_OFF    + 786432L)
#define GSIG_OFF (QKV_OFF  + 2359296L)
#define QN_OFF   (GSIG_OFF + 786432L)
#define KN_OFF   (QN_OFF   + 786432L)
#define OB_OFF   (KN_OFF   + 786432L)
#define BIAS_OFF (OB_OFF   + 786432L)
// end = 25169920 floats = 100.7 MB

__global__ __launch_bounds__(256) void k_prep(const float* __restrict__ pnw,
                                              const float* __restrict__ pnb,
                                              const float* __restrict__ bw,
                                              float* __restrict__ ws) {
    int t = threadIdx.x;
    for (int idx = t; idx < 2048; idx += 256)
        ws[WC_OFF + idx] = pnw[idx >> 4] * bw[idx];
    if (t < 16) {
        float a = 0.f, b = 0.f;
        for (int e = 0; e < 128; e++) { a += pnb[e] * bw[e*16 + t]; b += pnw[e] * bw[e*16 + t]; }
        ws[C12_OFF + t] = a;        // c1
        ws[C12_OFF + 16 + t] = b;   // c2
    }
}

// LayerNorm over 512 contiguous-ish elems: one block per row, 256 threads x 2 elems
__global__ __launch_bounds__(256) void k_ln512(const float* __restrict__ in, long ld, long col0,
                                               const float* __restrict__ w, const float* __restrict__ bp,
                                               float* __restrict__ out) {
    int r = blockIdx.x, t = threadIdx.x;
    const float* src = in + (long)r * ld + col0;
    float v0 = src[t], v1 = src[t + 256];
    float s1 = v0 + v1, s2 = v0*v0 + v1*v1;
    __shared__ float red[16];
    #pragma unroll
    for (int off = 32; off > 0; off >>= 1) {
        s1 += __shfl_down(s1, off, 64);
        s2 += __shfl_down(s2, off, 64);
    }
    int wid = t >> 6, lane = t & 63;
    if (lane == 0) { red[wid] = s1; red[wid + 4] = s2; }
    __syncthreads();
    if (t == 0) {
        float a = red[0]+red[1]+red[2]+red[3];
        float c = red[4]+red[5]+red[6]+red[7];
        float mean = a / 512.f;
        float var  = c / 512.f - mean*mean;
        red[8] = mean; red[9] = rsqrtf(var + 1e-5f);
    }
    __syncthreads();
    float mean = red[8], rstd = red[9];
    out[(long)r*512 + t]       = (v0 - mean) * rstd * w[t]       + bp[t];
    out[(long)r*512 + t + 256] = (v1 - mean) * rstd * w[t + 256] + bp[t + 256];
}

// fused [qkv | g] GEMM: x(1536x512) @ {qkv_w(512x1536), g_w(512x512)}; sigmoid folded into g
__global__ __launch_bounds__(256) void k_qkvg(const float* __restrict__ x,
                                              const float* __restrict__ qkv_w, const float* __restrict__ qkv_b,
                                              const float* __restrict__ g_w,  const float* __restrict__ g_b,
                                              float* __restrict__ qkv_o, float* __restrict__ gsig) {
    __shared__ float As[16][64];
    __shared__ float Bs[16][64];
    int bx = blockIdx.x, by = blockIdx.y, t = threadIdx.x;
    bool isg = (bx >= 24);
    const float* Wp = isg ? g_w : qkv_w;
    const float* bp = isg ? g_b : qkv_b;
    long ldw = isg ? 512 : 1536;
    int c0 = isg ? (bx - 24) * 64 : bx * 64;
    int tr = t >> 4, tc = t & 15;
    int am = t >> 2, ak = (t & 3) * 4;
    int bk = t >> 4, bc = (t & 15) * 4;
    const float* xrow = x + (long)(by*64 + am)*512 + ak;
    float acc[4][4] = {};
    for (int kt = 0; kt < 32; kt++) {
        float4 av = *(const float4*)(xrow + kt*16);
        float4 bv = *(const float4*)(Wp + (long)(kt*16 + bk)*ldw + c0 + bc);
        As[ak+0][am] = av.x; As[ak+1][am] = av.y; As[ak+2][am] = av.z; As[ak+3][am] = av.w;
        *(float4*)&Bs[bk][bc] = bv;
        __syncthreads();
        #pragma unroll
        for (int k = 0; k < 16; k++) {
            float4 a4 = *(const float4*)&As[k][tr*4];
            float4 b4 = *(const float4*)&Bs[k][tc*4];
            float ar[4] = {a4.x, a4.y, a4.z, a4.w};
            float br[4] = {b4.x, b4.y, b4.z, b4.w};
            #pragma unroll
            for (int r = 0; r < 4; r++)
                #pragma unroll
                for (int c = 0; c < 4; c++)
                    acc[r][c] = fmaf(ar[r], br[c], acc[r][c]);
        }
        __syncthreads();
    }
    #pragma unroll
    for (int r = 0; r < 4; r++) {
        int row = by*64 + tr*4 + r;
        #pragma unroll
        for (int c = 0; c < 4; c++) {
            int col = c0 + tc*4 + c;
            float val = acc[r][c] + bp[col];
            if (!isg) qkv_o[(long)row*1536 + col] = val;
            else      gsig[(long)row*512 + col] = 1.f / (1.f + __expf(-val));
        }
    }
}

// pair LN + bias einsum + mask; tile = one (b,i) row x 128 j's
__global__ __launch_bounds__(256) void k_bias(const float* __restrict__ pair,
                                              const int* __restrict__ mask,
                                              const float* __restrict__ wsbase,
                                              float* __restrict__ bias_o) {
    __shared__ float pb[128 * 130];
    __shared__ float stats_m[128];
    __shared__ float stats_r[128];
    __shared__ float wc[2048];
    __shared__ float c12[32];
    int bid = blockIdx.x, t = threadIdx.x;
    int jt = bid % 6;
    int i  = (bid / 6) % 768;
    int b  = bid / (6 * 768);
    for (int idx = t; idx < 2048; idx += 256) wc[idx] = wsbase[WC_OFF + idx];
    if (t < 32) c12[t] = wsbase[C12_OFF + t];
    const float* src = pair + ((long)(b*NN + i)*NN + jt*128) * 128;
    // coalesced load + per-row stats + rotated LDS store
    for (int it = 0; it < 16; it++) {
        int f = t + it * 256;           // float4 index in tile
        int j = f >> 5, c = f & 31;
        float4 v = *(const float4*)(src + (long)f * 4);
        float s1 = v.x + v.y + v.z + v.w;
        float s2 = v.x*v.x + v.y*v.y + v.z*v.z + v.w*v.w;
        #pragma unroll
        for (int off = 16; off > 0; off >>= 1) {
            s1 += __shfl_down(s1, off, 32);
            s2 += __shfl_down(s2, off, 32);
        }
        if (c == 0) {
            float mean = s1 / 128.f;
            float var  = s2 / 128.f - mean*mean;
            stats_m[j] = mean;
            stats_r[j] = rsqrtf(var + 1e-5f);
        }
        int rot = (j >> 2) * 2;
        int e0 = (c*4 + rot) & 127;
        int eb = (e0 + 2) & 127;
        int base = j * 130;
        *(float2*)&pb[base + e0] = make_float2(v.x, v.y);
        *(float2*)&pb[base + eb] = make_float2(v.z, v.w);
    }
    __syncthreads();
    int jr = t >> 3, hr = (t >> 1) & 3, ec = t & 1;
    const float* pr[4];
    #pragma unroll
    for (int jj = 0; jj < 4; jj++) pr[jj] = &pb[(jr*4 + jj) * 130];
    int rot = jr * 2;
    float acc[4][4] = {};
    int es = (ec*64 + rot) & 127;
    #pragma unroll
    for (int e2 = 0; e2 < 32; e2++) {
        int e = ec*64 + e2*2;
        float4 wa = *(const float4*)&wc[e*16 + hr*4];
        float4 wb = *(const float4*)&wc[e*16 + 16 + hr*4];
        float war[4] = {wa.x, wa.y, wa.z, wa.w};
        float wbr[4] = {wb.x, wb.y, wb.z, wb.w};
        #pragma unroll
        for (int jj = 0; jj < 4; jj++) {
            float2 pv = *(const float2*)&pr[jj][es];
            #pragma unroll
            for (int hh = 0; hh < 4; hh++)
                acc[jj][hh] = fmaf(pv.x, war[hh], fmaf(pv.y, wbr[hh], acc[jj][hh]));
        }
        es = (es + 2) & 127;
    }
    #pragma unroll
    for (int jj = 0; jj < 4; jj++)
        #pragma unroll
        for (int hh = 0; hh < 4; hh++)
            acc[jj][hh] += __shfl_xor(acc[jj][hh], 1, 64);
    if (ec == 0) {
        long ibase = (long)(b*NN + i)*NN + jt*128;
        #pragma unroll
        for (int jj = 0; jj < 4; jj++) {
            int j = jr*4 + jj;
            int mk = mask[ibase + j];
            float mu = stats_m[j], rs = stats_r[j];
            float4 ov;
            float tmp[4];
            #pragma unroll
            for (int hh = 0; hh < 4; hh++) {
                int h = hr*4 + hh;
                tmp[hh] = mk ? (rs * acc[jj][hh] - rs * mu * c12[16 + h] + c12[h]) : -10000.f;
            }
            ov.x = tmp[0]; ov.y = tmp[1]; ov.z = tmp[2]; ov.w = tmp[3];
            *(float4*)&bias_o[(ibase + j)*16 + hr*4] = ov;
        }
    }
}

// flash attention: thread = (query row in 16-tile, head); online softmax over 768 j
__global__ __launch_bounds__(256) void k_attn(const float* __restrict__ qn,
                                              const float* __restrict__ kn,
                                              const float* __restrict__ qkv,
                                              const float* __restrict__ gsig,
                                              const float* __restrict__ bias,
                                              float* __restrict__ obuf) {
    int bid = blockIdx.x;
    int b = bid / 48, it = bid % 48;
    int t = threadIdx.x;
    int il = t >> 4, h = t & 15;
    int i = it*16 + il;
    long qb = (long)(b*NN + i)*512 + h*32;
    float4 q[8];
    #pragma unroll
    for (int s = 0; s < 8; s++) q[s] = *(const float4*)(qn + qb + s*4);
    float m = -1e30f, l = 0.f;
    float4 o[8];
    #pragma unroll
    for (int s = 0; s < 8; s++) o[s] = make_float4(0.f, 0.f, 0.f, 0.f);
    long bias_row = (long)(b*NN + i)*NN*16 + h;
    // prefetch j=0 K row + bias
    float4 kc[8];
    {
        const float* kp = kn + (long)(b*NN)*512 + h*32;
        #pragma unroll
        for (int s = 0; s < 8; s++) kc[s] = ((const float4*)kp)[s];
    }
    float bias_c = bias[bias_row];
    for (int j = 0; j < NN; j++) {
        float4 knx[8];
        float bias_n = 0.f;
        if (j + 1 < NN) {
            const float* kp = kn + (long)(b*NN + j + 1)*512 + h*32;
            #pragma unroll
            for (int s = 0; s < 8; s++) knx[s] = ((const float4*)kp)[s];
            bias_n = bias[bias_row + (long)(j + 1)*16];
        }
        float s = 0.f;
        #pragma unroll
        for (int s4 = 0; s4 < 8; s4++)
            s += kc[s4].x*q[s4].x + kc[s4].y*q[s4].y + kc[s4].z*q[s4].z + kc[s4].w*q[s4].w;
        s = s * 0.17677669529663687f + bias_c;
        float mn = fmaxf(m, s);
        float corr = __expf(m - mn);
        float p = __expf(s - mn);
        l = l * corr + p;
        m = mn;
        const float* vp = qkv + (long)(b*NN + j)*1536 + 1024 + h*32;
        #pragma unroll
        for (int s4 = 0; s4 < 8; s4++) {
            float4 vv = ((const float4*)vp)[s4];
            o[s4].x = o[s4].x*corr + p*vv.x;
            o[s4].y = o[s4].y*corr + p*vv.y;
            o[s4].z = o[s4].z*corr + p*vv.z;
            o[s4].w = o[s4].w*corr + p*vv.w;
        }
        #pragma unroll
        for (int s4 = 0; s4 < 8; s4++) kc[s4] = knx[s4];
        bias_c = bias_n;
    }
    float inv = 1.f / l;
    long ob = (long)(b*NN + i)*512 + h*32;
    #pragma unroll
    for (int s4 = 0; s4 < 8; s4++) {
        float4 gv = *(const float4*)(gsig + ob + s4*4);
        float4 r;
        r.x = gv.x * o[s4].x * inv;
        r.y = gv.y * o[s4].y * inv;
        r.z = gv.z * o[s4].z * inv;
        r.w = gv.w * o[s4].w * inv;
        *(float4*)(obuf + ob + s4*4) = r;
    }
}

// out projection: obuf(1536x512) @ out_w(512x512) + out_b
__global__ __launch_bounds__(256) void k_out(const float* __restrict__ ob,
                                             const float* __restrict__ w,
                                             const float* __restrict__ bp,
                                             float* __restrict__ out) {
    __shared__ float As[16][64];
    __shared__ float Bs[16][64];
    int bx = blockIdx.x, by = blockIdx.y, t = threadIdx.x;
    int c0 = bx * 64;
    int tr = t >> 4, tc = t & 15;
    int am = t >> 2, ak = (t & 3) * 4;
    int bk = t >> 4, bc = (t & 15) * 4;
    const float* xrow = ob + (long)(by*64 + am)*512 + ak;
    float acc[4][4] = {};
    for (int kt = 0; kt < 32; kt++) {
        float4 av = *(const float4*)(xrow + kt*16);
        float4 bv = *(const float4*)(w + (long)(kt*16 + bk)*512 + c0 + bc);
        As[ak+0][am] = av.x; As[ak+1][am] = av.y; As[ak+2][am] = av.z; As[ak+3][am] = av.w;
        *(float4*)&Bs[bk][bc] = bv;
        __syncthreads();
        #pragma unroll
        for (int k = 0; k < 16; k++) {
            float4 a4 = *(const float4*)&As[k][tr*4];
            float4 b4 = *(const float4*)&Bs[k][tc*4];
            float ar[4] = {a4.x, a4.y, a4.z, a4.w};
            float br[4] = {b4.x, b4.y, b4.z, b4.w};
            #pragma unroll
            for (int r = 0; r < 4; r++)
                #pragma unroll
                for (int c = 0; c < 4; c++)
                    acc[r][c] = fmaf(ar[r], br[c], acc[r][c]);
        }
        __syncthreads();
    }
    #pragma unroll
    for (int r = 0; r < 4; r++) {
        int row = by*64 + tr*4 + r;
        #pragma unroll
        for (int c = 0; c < 4; c++) {
            int col = c0 + tc*4 + c;
            out[(long)row*512 + col] = acc[r][c] + bp[col];
        }
    }
}

extern "C" void kernel_launch(void* const* d_in, const int* in_sizes, int n_in,
                              void* d_out, int out_size, void* d_ws, size_t ws_size,
                              hipStream_t stream) {
    const float* node_feats = (const float*)d_in[0];
    const float* pair_feats = (const float*)d_in[1];
    const int*   mask       = (const int*)d_in[2];
    const float* node_w     = (const float*)d_in[3];
    const float* node_b     = (const float*)d_in[4];
    const float* qkv_w      = (const float*)d_in[5];
    const float* qkv_b      = (const float*)d_in[6];
    const float* g_w        = (const float*)d_in[7];
    const float* g_b        = (const float*)d_in[8];
    const float* qln_w      = (const float*)d_in[9];
    const float* qln_b      = (const float*)d_in[10];
    const float* kln_w      = (const float*)d_in[11];
    const float* kln_b      = (const float*)d_in[12];
    const float* pnw        = (const float*)d_in[13];
    const float* pnb        = (const float*)d_in[14];
    const float* bias_w     = (const float*)d_in[15];
    const float* out_w      = (const float*)d_in[16];
    const float* out_b      = (const float*)d_in[17];
    float* out = (float*)d_out;
    float* ws  = (float*)d_ws;

    float* x_buf    = ws + X_OFF;
    float* qkv_buf  = ws + QKV_OFF;
    float* gsig_buf = ws + GSIG_OFF;
    float* qn_buf   = ws + QN_OFF;
    float* kn_buf   = ws + KN_OFF;
    float* ob_buf   = ws + OB_OFF;
    float* bias_buf = ws + BIAS_OFF;

    k_prep<<<1, 256, 0, stream>>>(pnw, pnb, bias_w, ws);
    k_ln512<<<ROWS, 256, 0, stream>>>(node_feats, 512, 0, node_w, node_b, x_buf);
    k_qkvg<<<dim3(32, 24), 256, 0, stream>>>(x_buf, qkv_w, qkv_b, g_w, g_b, qkv_buf, gsig_buf);
    k_ln512<<<ROWS, 256, 0, stream>>>(qkv_buf, 1536, 0,   qln_w, qln_b, qn_buf);
    k_ln512<<<ROWS, 256, 0, stream>>>(qkv_buf, 1536, 512, kln_w, kln_b, kn_buf);
    k_bias<<<BB * 768 * 6, 256, 0, stream>>>(pair_feats, mask, ws, bias_buf);
    k_attn<<<BB * 48, 256, 0, stream>>>(qn_buf, kn_buf, qkv_buf, gsig_buf, bias_buf, ob_buf);
    k_out<<<dim3(8, 24), 256, 0, stream>>>(ob_buf, out_w, out_b, out);
}

// Round 3
// 1204.592 us; speedup vs baseline: 2.0384x; 2.0384x over previous
//
#include <hip/hip_runtime.h>
#include <hip/hip_bf16.h>
#include <math.h>

#define BB 2
#define NN 768
#define DD 512
#define HH 16
#define DHH 32
#define PDD 128
#define ROWS (BB*NN)          // 1536

// workspace offsets (floats)
#define WC_OFF   0L           // 2048: pnw[e]*bias_w[e,h]
#define C12_OFF  2048L        // 16 c1 + 16 c2
#define X_OFF    4096L
#define QKV_OFF  (X_OFF    + 786432L)
#define GSIG_OFF (QKV_OFF  + 2359296L)
#define QN_OFF   (GSIG_OFF + 786432L)
#define KN_OFF   (QN_OFF   + 786432L)
#define OB_OFF   (KN_OFF   + 786432L)
#define BIAS_OFF (OB_OFF   + 786432L)   // layout: (b,h,i,j) = ((b*16+h)*768 + i)*768 + j
// end = 25169920 floats = 100.7 MB

__global__ __launch_bounds__(256) void k_prep(const float* __restrict__ pnw,
                                              const float* __restrict__ pnb,
                                              const float* __restrict__ bw,
                                              float* __restrict__ ws) {
    int t = threadIdx.x;
    for (int idx = t; idx < 2048; idx += 256)
        ws[WC_OFF + idx] = pnw[idx >> 4] * bw[idx];
    if (t < 16) {
        float a = 0.f, b = 0.f;
        for (int e = 0; e < 128; e++) { a += pnb[e] * bw[e*16 + t]; b += pnw[e] * bw[e*16 + t]; }
        ws[C12_OFF + t] = a;        // c1
        ws[C12_OFF + 16 + t] = b;   // c2
    }
}

// LayerNorm over 512 elems: one block per row
__global__ __launch_bounds__(256) void k_ln512(const float* __restrict__ in, long ld, long col0,
                                               const float* __restrict__ w, const float* __restrict__ bp,
                                               float* __restrict__ out) {
    int r = blockIdx.x, t = threadIdx.x;
    const float* src = in + (long)r * ld + col0;
    float v0 = src[t], v1 = src[t + 256];
    float s1 = v0 + v1, s2 = v0*v0 + v1*v1;
    __shared__ float red[16];
    #pragma unroll
    for (int off = 32; off > 0; off >>= 1) {
        s1 += __shfl_down(s1, off, 64);
        s2 += __shfl_down(s2, off, 64);
    }
    int wid = t >> 6, lane = t & 63;
    if (lane == 0) { red[wid] = s1; red[wid + 4] = s2; }
    __syncthreads();
    if (t == 0) {
        float a = red[0]+red[1]+red[2]+red[3];
        float c = red[4]+red[5]+red[6]+red[7];
        float mean = a / 512.f;
        float var  = c / 512.f - mean*mean;
        red[8] = mean; red[9] = rsqrtf(var + 1e-5f);
    }
    __syncthreads();
    float mean = red[8], rstd = red[9];
    out[(long)r*512 + t]       = (v0 - mean) * rstd * w[t]       + bp[t];
    out[(long)r*512 + t + 256] = (v1 - mean) * rstd * w[t + 256] + bp[t + 256];
}

// fused [qkv | g] GEMM; sigmoid folded into g
__global__ __launch_bounds__(256) void k_qkvg(const float* __restrict__ x,
                                              const float* __restrict__ qkv_w, const float* __restrict__ qkv_b,
                                              const float* __restrict__ g_w,  const float* __restrict__ g_b,
                                              float* __restrict__ qkv_o, float* __restrict__ gsig) {
    __shared__ float As[16][64];
    __shared__ float Bs[16][64];
    int bx = blockIdx.x, by = blockIdx.y, t = threadIdx.x;
    bool isg = (bx >= 24);
    const float* Wp = isg ? g_w : qkv_w;
    const float* bp = isg ? g_b : qkv_b;
    long ldw = isg ? 512 : 1536;
    int c0 = isg ? (bx - 24) * 64 : bx * 64;
    int tr = t >> 4, tc = t & 15;
    int am = t >> 2, ak = (t & 3) * 4;
    int bk = t >> 4, bc = (t & 15) * 4;
    const float* xrow = x + (long)(by*64 + am)*512 + ak;
    float acc[4][4] = {};
    for (int kt = 0; kt < 32; kt++) {
        float4 av = *(const float4*)(xrow + kt*16);
        float4 bv = *(const float4*)(Wp + (long)(kt*16 + bk)*ldw + c0 + bc);
        As[ak+0][am] = av.x; As[ak+1][am] = av.y; As[ak+2][am] = av.z; As[ak+3][am] = av.w;
        *(float4*)&Bs[bk][bc] = bv;
        __syncthreads();
        #pragma unroll
        for (int k = 0; k < 16; k++) {
            float4 a4 = *(const float4*)&As[k][tr*4];
            float4 b4 = *(const float4*)&Bs[k][tc*4];
            float ar[4] = {a4.x, a4.y, a4.z, a4.w};
            float br[4] = {b4.x, b4.y, b4.z, b4.w};
            #pragma unroll
            for (int r = 0; r < 4; r++)
                #pragma unroll
                for (int c = 0; c < 4; c++)
                    acc[r][c] = fmaf(ar[r], br[c], acc[r][c]);
        }
        __syncthreads();
    }
    #pragma unroll
    for (int r = 0; r < 4; r++) {
        int row = by*64 + tr*4 + r;
        #pragma unroll
        for (int c = 0; c < 4; c++) {
            int col = c0 + tc*4 + c;
            float val = acc[r][c] + bp[col];
            if (!isg) qkv_o[(long)row*1536 + col] = val;
            else      gsig[(long)row*512 + col] = 1.f / (1.f + __expf(-val));
        }
    }
}

// pair LN + bias einsum + mask; writes (b,h,i,j) layout
__global__ __launch_bounds__(256) void k_bias(const float* __restrict__ pair,
                                              const int* __restrict__ mask,
                                              const float* __restrict__ wsbase,
                                              float* __restrict__ bias_o) {
    __shared__ float pb[128 * 130];
    __shared__ float stats_m[128];
    __shared__ float stats_r[128];
    __shared__ float wc[2048];
    __shared__ float c12[32];
    int bid = blockIdx.x, t = threadIdx.x;
    int jt = bid % 6;
    int i  = (bid / 6) % 768;
    int b  = bid / (6 * 768);
    for (int idx = t; idx < 2048; idx += 256) wc[idx] = wsbase[WC_OFF + idx];
    if (t < 32) c12[t] = wsbase[C12_OFF + t];
    const float* src = pair + ((long)(b*NN + i)*NN + jt*128) * 128;
    for (int it = 0; it < 16; it++) {
        int f = t + it * 256;
        int j = f >> 5, c = f & 31;
        float4 v = *(const float4*)(src + (long)f * 4);
        float s1 = v.x + v.y + v.z + v.w;
        float s2 = v.x*v.x + v.y*v.y + v.z*v.z + v.w*v.w;
        #pragma unroll
        for (int off = 16; off > 0; off >>= 1) {
            s1 += __shfl_down(s1, off, 32);
            s2 += __shfl_down(s2, off, 32);
        }
        if (c == 0) {
            float mean = s1 / 128.f;
            float var  = s2 / 128.f - mean*mean;
            stats_m[j] = mean;
            stats_r[j] = rsqrtf(var + 1e-5f);
        }
        int rot = (j >> 2) * 2;
        int e0 = (c*4 + rot) & 127;
        int eb = (e0 + 2) & 127;
        int base = j * 130;
        *(float2*)&pb[base + e0] = make_float2(v.x, v.y);
        *(float2*)&pb[base + eb] = make_float2(v.z, v.w);
    }
    __syncthreads();
    int jr = t >> 3, hr = (t >> 1) & 3, ec = t & 1;
    const float* pr[4];
    #pragma unroll
    for (int jj = 0; jj < 4; jj++) pr[jj] = &pb[(jr*4 + jj) * 130];
    int rot = jr * 2;
    float acc[4][4] = {};
    int es = (ec*64 + rot) & 127;
    #pragma unroll
    for (int e2 = 0; e2 < 32; e2++) {
        int e = ec*64 + e2*2;
        float4 wa = *(const float4*)&wc[e*16 + hr*4];
        float4 wb = *(const float4*)&wc[e*16 + 16 + hr*4];
        float war[4] = {wa.x, wa.y, wa.z, wa.w};
        float wbr[4] = {wb.x, wb.y, wb.z, wb.w};
        #pragma unroll
        for (int jj = 0; jj < 4; jj++) {
            float2 pv = *(const float2*)&pr[jj][es];
            #pragma unroll
            for (int hh = 0; hh < 4; hh++)
                acc[jj][hh] = fmaf(pv.x, war[hh], fmaf(pv.y, wbr[hh], acc[jj][hh]));
        }
        es = (es + 2) & 127;
    }
    #pragma unroll
    for (int jj = 0; jj < 4; jj++)
        #pragma unroll
        for (int hh = 0; hh < 4; hh++)
            acc[jj][hh] += __shfl_xor(acc[jj][hh], 1, 64);
    if (ec == 0) {
        long mbase = (long)(b*NN + i)*NN + jt*128 + jr*4;
        int4 mk4 = *(const int4*)&mask[mbase];
        int mks[4] = {mk4.x, mk4.y, mk4.z, mk4.w};
        float rs4[4], rm4[4];
        #pragma unroll
        for (int jj = 0; jj < 4; jj++) {
            int j = jr*4 + jj;
            rs4[jj] = stats_r[j];
            rm4[jj] = stats_r[j] * stats_m[j];
        }
        #pragma unroll
        for (int hh = 0; hh < 4; hh++) {
            int h = hr*4 + hh;
            float c2h = c12[16 + h], c1h = c12[h];
            float vals[4];
            #pragma unroll
            for (int jj = 0; jj < 4; jj++)
                vals[jj] = mks[jj] ? (rs4[jj] * acc[jj][hh] - rm4[jj] * c2h + c1h) : -10000.f;
            float4 ov = make_float4(vals[0], vals[1], vals[2], vals[3]);
            *(float4*)&bias_o[((long)(b*16 + h)*NN + i)*NN + jt*128 + jr*4] = ov;
        }
    }
}

// flash attention: block = (i-tile of 16 rows, b*16+h); 128 threads = 8 row-pairs x 16 j-slots
__global__ __launch_bounds__(128) void k_attn(const float* __restrict__ qn,
                                              const float* __restrict__ kn,
                                              const float* __restrict__ qkv,
                                              const float* __restrict__ gsig,
                                              const float* __restrict__ bias,
                                              float* __restrict__ obuf) {
    __shared__ float Ks[64][36];
    __shared__ float Vs[64][36];
    int it = blockIdx.x, bh = blockIdx.y;
    int b = bh >> 4, h = bh & 15;
    int t = threadIdx.x;
    int rg = t >> 4, s = t & 15;
    int i0 = it*16 + rg*2;                 // first of the 2 rows this thread owns
    const float* qp = qn + ((long)(b*NN) + i0)*512 + h*32;
    float4 q0[8], q1[8];
    #pragma unroll
    for (int c = 0; c < 8; c++) {
        q0[c] = ((const float4*)qp)[c];
        q1[c] = ((const float4*)(qp + 512))[c];
    }
    float m0 = -1e30f, m1 = -1e30f, l0 = 0.f, l1 = 0.f;
    float4 o0[8], o1[8];
    #pragma unroll
    for (int c = 0; c < 8; c++) { o0[c] = make_float4(0,0,0,0); o1[c] = make_float4(0,0,0,0); }
    const long bias0 = ((long)bh*NN + i0)*NN;
    const float scale = 0.17677669529663687f;

    for (int jt = 0; jt < 12; jt++) {
        int j0 = jt*64;
        __syncthreads();
        #pragma unroll
        for (int k = 0; k < 4; k++) {
            int f = t + k*128;
            int row = f >> 3, ch = (f & 7)*4;
            *(float4*)&Ks[row][ch] = *(const float4*)(kn  + ((long)(b*NN) + j0 + row)*512  + h*32 + ch);
            *(float4*)&Vs[row][ch] = *(const float4*)(qkv + ((long)(b*NN) + j0 + row)*1536 + 1024 + h*32 + ch);
        }
        __syncthreads();
        #pragma unroll
        for (int st = 0; st < 4; st++) {
            int j = s + st*16;
            float d0 = 0.f, d1 = 0.f;
            #pragma unroll
            for (int c = 0; c < 8; c++) {
                float4 kv = *(const float4*)&Ks[j][c*4];
                d0 = fmaf(kv.x, q0[c].x, d0); d0 = fmaf(kv.y, q0[c].y, d0);
                d0 = fmaf(kv.z, q0[c].z, d0); d0 = fmaf(kv.w, q0[c].w, d0);
                d1 = fmaf(kv.x, q1[c].x, d1); d1 = fmaf(kv.y, q1[c].y, d1);
                d1 = fmaf(kv.z, q1[c].z, d1); d1 = fmaf(kv.w, q1[c].w, d1);
            }
            float b0v = bias[bias0 + j0 + j];
            float b1v = bias[bias0 + NN + j0 + j];
            float s0 = fmaf(d0, scale, b0v);
            float s1 = fmaf(d1, scale, b1v);
            float mn0 = fmaxf(m0, s0), mn1 = fmaxf(m1, s1);
            float p0 = __expf(s0 - mn0), p1 = __expf(s1 - mn1);
            if (__any((s0 > m0) || (s1 > m1))) {
                float c0 = __expf(m0 - mn0), c1 = __expf(m1 - mn1);
                l0 = l0*c0 + p0; l1 = l1*c1 + p1;
                m0 = mn0; m1 = mn1;
                #pragma unroll
                for (int c = 0; c < 8; c++) {
                    float4 vv = *(const float4*)&Vs[j][c*4];
                    o0[c].x = fmaf(o0[c].x, c0, p0*vv.x); o0[c].y = fmaf(o0[c].y, c0, p0*vv.y);
                    o0[c].z = fmaf(o0[c].z, c0, p0*vv.z); o0[c].w = fmaf(o0[c].w, c0, p0*vv.w);
                    o1[c].x = fmaf(o1[c].x, c1, p1*vv.x); o1[c].y = fmaf(o1[c].y, c1, p1*vv.y);
                    o1[c].z = fmaf(o1[c].z, c1, p1*vv.z); o1[c].w = fmaf(o1[c].w, c1, p1*vv.w);
                }
            } else {
                l0 += p0; l1 += p1;
                #pragma unroll
                for (int c = 0; c < 8; c++) {
                    float4 vv = *(const float4*)&Vs[j][c*4];
                    o0[c].x = fmaf(p0, vv.x, o0[c].x); o0[c].y = fmaf(p0, vv.y, o0[c].y);
                    o0[c].z = fmaf(p0, vv.z, o0[c].z); o0[c].w = fmaf(p0, vv.w, o0[c].w);
                    o1[c].x = fmaf(p1, vv.x, o1[c].x); o1[c].y = fmaf(p1, vv.y, o1[c].y);
                    o1[c].z = fmaf(p1, vv.z, o1[c].z); o1[c].w = fmaf(p1, vv.w, o1[c].w);
                }
            }
        }
    }
    // merge the 16 slot-partials (lanes within 16-group, same wave)
    #pragma unroll
    for (int mk = 1; mk < 16; mk <<= 1) {
        float mo0 = __shfl_xor(m0, mk, 64), mo1 = __shfl_xor(m1, mk, 64);
        float lo0 = __shfl_xor(l0, mk, 64), lo1 = __shfl_xor(l1, mk, 64);
        float nm0 = fmaxf(m0, mo0), nm1 = fmaxf(m1, mo1);
        float a0 = __expf(m0 - nm0), b0 = __expf(mo0 - nm0);
        float a1 = __expf(m1 - nm1), b1 = __expf(mo1 - nm1);
        l0 = l0*a0 + lo0*b0; l1 = l1*a1 + lo1*b1;
        m0 = nm0; m1 = nm1;
        #pragma unroll
        for (int c = 0; c < 8; c++) {
            float4 t0, t1;
            t0.x = __shfl_xor(o0[c].x, mk, 64); t0.y = __shfl_xor(o0[c].y, mk, 64);
            t0.z = __shfl_xor(o0[c].z, mk, 64); t0.w = __shfl_xor(o0[c].w, mk, 64);
            t1.x = __shfl_xor(o1[c].x, mk, 64); t1.y = __shfl_xor(o1[c].y, mk, 64);
            t1.z = __shfl_xor(o1[c].z, mk, 64); t1.w = __shfl_xor(o1[c].w, mk, 64);
            o0[c].x = fmaf(t0.x, b0, o0[c].x*a0); o0[c].y = fmaf(t0.y, b0, o0[c].y*a0);
            o0[c].z = fmaf(t0.z, b0, o0[c].z*a0); o0[c].w = fmaf(t0.w, b0, o0[c].w*a0);
            o1[c].x = fmaf(t1.x, b1, o1[c].x*a1); o1[c].y = fmaf(t1.y, b1, o1[c].y*a1);
            o1[c].z = fmaf(t1.z, b1, o1[c].z*a1); o1[c].w = fmaf(t1.w, b1, o1[c].w*a1);
        }
    }
    // epilogue: lane s -> row (s>>3), float4 chunk (s&7); select via cndmask chain
    int rsel = s >> 3, cs = s & 7;
    float4 a0 = o0[0], a1 = o1[0];
    #pragma unroll
    for (int k = 1; k < 8; k++) {
        bool c = (cs == k);
        a0.x = c ? o0[k].x : a0.x; a0.y = c ? o0[k].y : a0.y;
        a0.z = c ? o0[k].z : a0.z; a0.w = c ? o0[k].w : a0.w;
        a1.x = c ? o1[k].x : a1.x; a1.y = c ? o1[k].y : a1.y;
        a1.z = c ? o1[k].z : a1.z; a1.w = c ? o1[k].w : a1.w;
    }
    float4 ov;
    ov.x = rsel ? a1.x : a0.x; ov.y = rsel ? a1.y : a0.y;
    ov.z = rsel ? a1.z : a0.z; ov.w = rsel ? a1.w : a0.w;
    float inv = 1.f / (rsel ? l1 : l0);
    long base = ((long)(b*NN) + i0 + rsel)*512 + h*32 + cs*4;
    float4 g = *(const float4*)(gsig + base);
    float4 r;
    r.x = g.x * ov.x * inv; r.y = g.y * ov.y * inv;
    r.z = g.z * ov.z * inv; r.w = g.w * ov.w * inv;
    *(float4*)(obuf + base) = r;
}

// out projection: obuf(1536x512) @ out_w(512x512) + out_b
__global__ __launch_bounds__(256) void k_out(const float* __restrict__ ob,
                                             const float* __restrict__ w,
                                             const float* __restrict__ bp,
                                             float* __restrict__ out) {
    __shared__ float As[16][64];
    __shared__ float Bs[16][64];
    int bx = blockIdx.x, by = blockIdx.y, t = threadIdx.x;
    int c0 = bx * 64;
    int tr = t >> 4, tc = t & 15;
    int am = t >> 2, ak = (t & 3) * 4;
    int bk = t >> 4, bc = (t & 15) * 4;
    const float* xrow = ob + (long)(by*64 + am)*512 + ak;
    float acc[4][4] = {};
    for (int kt = 0; kt < 32; kt++) {
        float4 av = *(const float4*)(xrow + kt*16);
        float4 bv = *(const float4*)(w + (long)(kt*16 + bk)*512 + c0 + bc);
        As[ak+0][am] = av.x; As[ak+1][am] = av.y; As[ak+2][am] = av.z; As[ak+3][am] = av.w;
        *(float4*)&Bs[bk][bc] = bv;
        __syncthreads();
        #pragma unroll
        for (int k = 0; k < 16; k++) {
            float4 a4 = *(const float4*)&As[k][tr*4];
            float4 b4 = *(const float4*)&Bs[k][tc*4];
            float ar[4] = {a4.x, a4.y, a4.z, a4.w};
            float br[4] = {b4.x, b4.y, b4.z, b4.w};
            #pragma unroll
            for (int r = 0; r < 4; r++)
                #pragma unroll
                for (int c = 0; c < 4; c++)
                    acc[r][c] = fmaf(ar[r], br[c], acc[r][c]);
        }
        __syncthreads();
    }
    #pragma unroll
    for (int r = 0; r < 4; r++) {
        int row = by*64 + tr*4 + r;
        #pragma unroll
        for (int c = 0; c < 4; c++) {
            int col = c0 + tc*4 + c;
            out[(long)row*512 + col] = acc[r][c] + bp[col];
        }
    }
}

extern "C" void kernel_launch(void* const* d_in, const int* in_sizes, int n_in,
                              void* d_out, int out_size, void* d_ws, size_t ws_size,
                              hipStream_t stream) {
    const float* node_feats = (const float*)d_in[0];
    const float* pair_feats = (const float*)d_in[1];
    const int*   mask       = (const int*)d_in[2];
    const float* node_w     = (const float*)d_in[3];
    const float* node_b     = (const float*)d_in[4];
    const float* qkv_w      = (const float*)d_in[5];
    const float* qkv_b      = (const float*)d_in[6];
    const float* g_w        = (const float*)d_in[7];
    const float* g_b        = (const float*)d_in[8];
    const float* qln_w      = (const float*)d_in[9];
    const float* qln_b      = (const float*)d_in[10];
    const float* kln_w      = (const float*)d_in[11];
    const float* kln_b      = (const float*)d_in[12];
    const float* pnw        = (const float*)d_in[13];
    const float* pnb        = (const float*)d_in[14];
    const float* bias_w     = (const float*)d_in[15];
    const float* out_w      = (const float*)d_in[16];
    const float* out_b      = (const float*)d_in[17];
    float* out = (float*)d_out;
    float* ws  = (float*)d_ws;

    float* x_buf    = ws + X_OFF;
    float* qkv_buf  = ws + QKV_OFF;
    float* gsig_buf = ws + GSIG_OFF;
    float* qn_buf   = ws + QN_OFF;
    float* kn_buf   = ws + KN_OFF;
    float* ob_buf   = ws + OB_OFF;
    float* bias_buf = ws + BIAS_OFF;

    k_prep<<<1, 256, 0, stream>>>(pnw, pnb, bias_w, ws);
    k_ln512<<<ROWS, 256, 0, stream>>>(node_feats, 512, 0, node_w, node_b, x_buf);
    k_qkvg<<<dim3(32, 24), 256, 0, stream>>>(x_buf, qkv_w, qkv_b, g_w, g_b, qkv_buf, gsig_buf);
    k_ln512<<<ROWS, 256, 0, stream>>>(qkv_buf, 1536, 0,   qln_w, qln_b, qn_buf);
    k_ln512<<<ROWS, 256, 0, stream>>>(qkv_buf, 1536, 512, kln_w, kln_b, kn_buf);
    k_bias<<<BB * 768 * 6, 256, 0, stream>>>(pair_feats, mask, ws, bias_buf);
    k_attn<<<dim3(48, 32), 128, 0, stream>>>(qn_buf, kn_buf, qkv_buf, gsig_buf, bias_buf, ob_buf);
    k_out<<<dim3(8, 24), 256, 0, stream>>>(ob_buf, out_w, out_b, out);
}